// Round 1
// baseline (1177.227 us; speedup 1.0000x reference)
//
#include <hip/hip_runtime.h>
#include <hip/hip_bf16.h>

#define D 128

// ---------- float-orderable encoding for atomicMax on f32 ----------
__device__ __forceinline__ unsigned encf(float x) {
    unsigned u = __float_as_uint(x);
    return (u & 0x80000000u) ? ~u : (u | 0x80000000u);
}
__device__ __forceinline__ float decf(unsigned u) {
    return (u & 0x80000000u) ? __uint_as_float(u & 0x7FFFFFFFu) : __uint_as_float(~u);
}

// ---------- pass A: summed[r] += m[e]  (128 threads per edge) ----------
__global__ void scatter_sum_kernel(const float* __restrict__ msg,
                                   const int* __restrict__ recv,
                                   float* __restrict__ summed, int E) {
    int tid = blockIdx.x * blockDim.x + threadIdx.x;
    int lane = tid & (D - 1);
    int e = tid >> 7;
    if (e >= E) return;
    int r = recv[e];
    atomicAdd(&summed[(size_t)r * D + lane], msg[(size_t)e * D + lane]);
}

// ---------- transpose 128x128 ----------
__global__ void transpose128_kernel(const float* __restrict__ in, float* __restrict__ out) {
    int j = threadIdx.x;
    int i = blockIdx.x;
    out[(size_t)j * D + i] = in[(size_t)i * D + j];
}

// ---------- Wvo = Wv @ Wo ; bvo = bv @ Wo ----------
__global__ void fold_wvo_kernel(const float* __restrict__ Wv, const float* __restrict__ Wo,
                                const float* __restrict__ bv,
                                float* __restrict__ Wvo, float* __restrict__ bvo) {
    int j = threadIdx.x;
    int i = blockIdx.x;
    if (i < D) {
        float acc = 0.f;
        for (int k = 0; k < D; ++k) acc += Wv[(size_t)i * D + k] * Wo[(size_t)k * D + j];
        Wvo[(size_t)i * D + j] = acc;
    } else {
        float acc = 0.f;
        for (int k = 0; k < D; ++k) acc += bv[k] * Wo[(size_t)k * D + j];
        bvo[j] = acc;
    }
}

// ---------- tiled GEMM: C[n][j] = sum_i A[n][i]*B[i][j] (+bias[j]) (+sattn[n]*bvec[j]) ----------
#define GN 32  // nodes per block
__global__ __launch_bounds__(256) void gemm128_kernel(
        const float* __restrict__ A, const float* __restrict__ B,
        float* __restrict__ C,
        const float* __restrict__ bias,     // [128] or null
        const float* __restrict__ sumexp,   // [N] or null -> rowscale = se/(se+1e-8)
        const float* __restrict__ bvec,     // [128] or null
        int N) {
    __shared__ float Bs[D * D];      // 64 KB
    __shared__ float As[GN * D];     // 16 KB
    int t = threadIdx.x;
    const float4* Bg4 = (const float4*)B;
    float4* Bs4 = (float4*)Bs;
#pragma unroll
    for (int k = 0; k < 16; ++k) Bs4[t + 256 * k] = Bg4[t + 256 * k];
    int n0 = blockIdx.x * GN;
    const float4* Ag4 = (const float4*)(A + (size_t)n0 * D);
    float4* As4 = (float4*)As;
#pragma unroll
    for (int k = 0; k < 4; ++k) As4[t + 256 * k] = Ag4[t + 256 * k];
    __syncthreads();

    int c = t & 31;      // col group: cols 4c..4c+3
    int slot = t >> 5;   // node slot 0..7 -> nodes slot+8u
    float4 acc[4];
#pragma unroll
    for (int u = 0; u < 4; ++u) acc[u] = make_float4(0.f, 0.f, 0.f, 0.f);
    const float4* Bsr = (const float4*)Bs;
    for (int i = 0; i < D; i += 4) {
        float4 a[4];
#pragma unroll
        for (int u = 0; u < 4; ++u) a[u] = *(const float4*)(As + (slot + 8 * u) * D + i);
#pragma unroll
        for (int ii = 0; ii < 4; ++ii) {
            float4 b = Bsr[(i + ii) * 32 + c];
#pragma unroll
            for (int u = 0; u < 4; ++u) {
                float av = (ii == 0) ? a[u].x : (ii == 1) ? a[u].y : (ii == 2) ? a[u].z : a[u].w;
                acc[u].x += av * b.x; acc[u].y += av * b.y;
                acc[u].z += av * b.z; acc[u].w += av * b.w;
            }
        }
    }
    float4 bias4 = bias ? ((const float4*)bias)[c] : make_float4(0.f, 0.f, 0.f, 0.f);
    float4 bv4 = bvec ? ((const float4*)bvec)[c] : make_float4(0.f, 0.f, 0.f, 0.f);
#pragma unroll
    for (int u = 0; u < 4; ++u) {
        int n = n0 + slot + 8 * u;
        if (n >= N) continue;
        float4 r = acc[u];
        r.x += bias4.x; r.y += bias4.y; r.z += bias4.z; r.w += bias4.w;
        if (sumexp) {
            float se = sumexp[n];
            float sa = se / (se + 1e-8f);
            r.x += sa * bv4.x; r.y += sa * bv4.y; r.z += sa * bv4.z; r.w += sa * bv4.w;
        }
        ((float4*)(C + (size_t)n * D))[c] = r;
    }
}

// ---------- qb[n] = sum_j queries[n][j]*bk[j]  (wave per node) ----------
__global__ void rowdot_kernel(const float* __restrict__ A, const float* __restrict__ v,
                              float* __restrict__ out, int N) {
    int g = blockIdx.x * blockDim.x + threadIdx.x;
    int lane = g & 63;
    int n = g >> 6;
    if (n >= N) return;
    const float2* a2 = (const float2*)(A + (size_t)n * D);
    const float2* v2 = (const float2*)v;
    float2 a = a2[lane], b = v2[lane];
    float s = a.x * b.x + a.y * b.y;
#pragma unroll
    for (int off = 32; off; off >>= 1) s += __shfl_down(s, off);
    if (lane == 0) out[n] = s;
}

// ---------- scores[e] = (m_e . qk[r] + qb[r]) / sqrt(D); atomicMax per node ----------
__global__ void score_kernel(const float* __restrict__ msg, const int* __restrict__ recv,
                             const float* __restrict__ qk, const float* __restrict__ qb,
                             float* __restrict__ scores, unsigned* __restrict__ maxenc, int E) {
    int g = blockIdx.x * blockDim.x + threadIdx.x;
    int lane = g & 63;
    int e = g >> 6;
    if (e >= E) return;
    int r = recv[e];
    const float2* m2 = (const float2*)(msg + (size_t)e * D);
    const float2* q2 = (const float2*)(qk + (size_t)r * D);
    float2 a = m2[lane], b = q2[lane];
    float s = a.x * b.x + a.y * b.y;
#pragma unroll
    for (int off = 32; off; off >>= 1) s += __shfl_down(s, off);
    if (lane == 0) {
        float sc = (s + qb[r]) * 0.088388347648318440550f;  // 1/sqrt(128)
        scores[e] = sc;
        atomicMax(&maxenc[r], encf(sc));
    }
}

// ---------- expS[e] = exp(scores[e]-max[r]); sumexp[r] += expS[e] ----------
__global__ void exp_kernel(const float* __restrict__ scores, const int* __restrict__ recv,
                           const unsigned* __restrict__ maxenc,
                           float* __restrict__ expS, float* __restrict__ sumexp, int E) {
    int e = blockIdx.x * blockDim.x + threadIdx.x;
    if (e >= E) return;
    int r = recv[e];
    float mx = decf(maxenc[r]);
    float ex = __expf(scores[e] - mx);
    expS[e] = ex;
    atomicAdd(&sumexp[r], ex);
}

// ---------- S[r] += (expS[e]/(sumexp[r]+1e-8)) * m[e] ----------
__global__ void weighted_scatter_kernel(const float* __restrict__ msg, const int* __restrict__ recv,
                                        const float* __restrict__ expS, const float* __restrict__ sumexp,
                                        float* __restrict__ S, int E) {
    int tid = blockIdx.x * blockDim.x + threadIdx.x;
    int lane = tid & (D - 1);
    int e = tid >> 7;
    if (e >= E) return;
    int r = recv[e];
    float w = expS[e] / (sumexp[r] + 1e-8f);
    atomicAdd(&S[(size_t)r * D + lane], w * msg[(size_t)e * D + lane]);
}

extern "C" void kernel_launch(void* const* d_in, const int* in_sizes, int n_in,
                              void* d_out, int out_size, void* d_ws, size_t ws_size,
                              hipStream_t stream) {
    const float* msg = (const float*)d_in[0];
    const int* recv = (const int*)d_in[1];
    const float* Wk = (const float*)d_in[3];
    const float* bk = (const float*)d_in[4];
    const float* Wv = (const float*)d_in[5];
    const float* bv = (const float*)d_in[6];
    const float* Wq = (const float*)d_in[7];
    const float* bq = (const float*)d_in[8];
    const float* Wo = (const float*)d_in[9];
    const float* bo = (const float*)d_in[10];
    float* out = (float*)d_out;

    int E = in_sizes[0] / D;
    int N = out_size / D;

    float* ws = (float*)d_ws;
    size_t o = 0;
    float* summed = ws + o; o += (size_t)N * D;
    float* S      = ws + o; o += (size_t)N * D;
    float* sumexp = ws + o; o += N;
    unsigned* maxenc = (unsigned*)(ws + o); o += N;
    size_t zero_floats = o;  // everything above must be zero-initialized
    float* queries = ws + o; o += (size_t)N * D;
    float* qk      = ws + o; o += (size_t)N * D;
    float* qb      = ws + o; o += N;
    float* scores  = ws + o; o += E;
    float* expS    = ws + o; o += E;
    float* WkT     = ws + o; o += D * D;
    float* Wvo     = ws + o; o += D * D;
    float* bvo     = ws + o; o += D;

    hipMemsetAsync(d_ws, 0, zero_floats * sizeof(float), stream);

    // independent weight prep
    transpose128_kernel<<<D, D, 0, stream>>>(Wk, WkT);
    fold_wvo_kernel<<<D + 1, D, 0, stream>>>(Wv, Wo, bv, Wvo, bvo);

    // pass A: segment-sum of messages
    {
        long long threads = (long long)E * D;
        scatter_sum_kernel<<<(int)((threads + 255) / 256), 256, 0, stream>>>(msg, recv, summed, E);
    }
    // queries = summed @ Wq + bq
    gemm128_kernel<<<(N + GN - 1) / GN, 256, 0, stream>>>(summed, Wq, queries, bq, nullptr, nullptr, N);
    // qk = queries @ Wk^T
    gemm128_kernel<<<(N + GN - 1) / GN, 256, 0, stream>>>(queries, WkT, qk, nullptr, nullptr, nullptr, N);
    // qb = queries . bk
    rowdot_kernel<<<(N * 64 + 255) / 256, 256, 0, stream>>>(queries, bk, qb, N);

    // pass B: scores + segment max
    score_kernel<<<(int)(((long long)E * 64 + 255) / 256), 256, 0, stream>>>(msg, recv, qk, qb, scores, maxenc, E);
    // exp + segment sum
    exp_kernel<<<(E + 255) / 256, 256, 0, stream>>>(scores, recv, maxenc, expS, sumexp, E);

    // pass C: weighted scatter of messages
    {
        long long threads = (long long)E * D;
        weighted_scatter_kernel<<<(int)((threads + 255) / 256), 256, 0, stream>>>(msg, recv, expS, sumexp, S, E);
    }
    // out = S @ (Wv@Wo) + sattn*(bv@Wo) + bo
    gemm128_kernel<<<(N + GN - 1) / GN, 256, 0, stream>>>(S, Wvo, out, bo, sumexp, bvo, N);
}

// Round 2
// 763.692 us; speedup vs baseline: 1.5415x; 1.5415x over previous
//
#include <hip/hip_runtime.h>
#include <hip/hip_bf16.h>

#define D 128
#define RSQRT_D 0.088388347648318440550f  // 1/sqrt(128)

// ============================ CSR build ============================

__global__ void hist_kernel(const int* __restrict__ recv, int* __restrict__ cnt, int E) {
    int e = blockIdx.x * blockDim.x + threadIdx.x;
    if (e >= E) return;
    atomicAdd(&cnt[recv[e]], 1);
}

#define SCAN_B 256
// per-block exclusive scan + block totals
__global__ void scan1_kernel(const int* __restrict__ cnt, int* __restrict__ excl,
                             int* __restrict__ bsum, int N) {
    __shared__ int tmp[SCAN_B];
    int i = blockIdx.x * SCAN_B + threadIdx.x;
    int v = (i < N) ? cnt[i] : 0;
    tmp[threadIdx.x] = v;
    __syncthreads();
#pragma unroll
    for (int off = 1; off < SCAN_B; off <<= 1) {
        int t = (threadIdx.x >= off) ? tmp[threadIdx.x - off] : 0;
        __syncthreads();
        tmp[threadIdx.x] += t;
        __syncthreads();
    }
    if (i < N) excl[i] = tmp[threadIdx.x] - v;
    if (threadIdx.x == SCAN_B - 1) bsum[blockIdx.x] = tmp[threadIdx.x];
}

// single-block exclusive scan of block totals (nb <= 256)
__global__ void scan2_kernel(int* __restrict__ bsum, int nb) {
    __shared__ int tmp[SCAN_B];
    int v = (threadIdx.x < nb) ? bsum[threadIdx.x] : 0;
    tmp[threadIdx.x] = v;
    __syncthreads();
#pragma unroll
    for (int off = 1; off < SCAN_B; off <<= 1) {
        int t = (threadIdx.x >= off) ? tmp[threadIdx.x - off] : 0;
        __syncthreads();
        tmp[threadIdx.x] += t;
        __syncthreads();
    }
    if (threadIdx.x < nb) bsum[threadIdx.x] = tmp[threadIdx.x] - v;
}

__global__ void scan3_kernel(const int* __restrict__ excl, const int* __restrict__ bsum,
                             int* __restrict__ start, int N, int E) {
    int i = blockIdx.x * SCAN_B + threadIdx.x;
    if (i < N) start[i] = excl[i] + bsum[blockIdx.x];
    if (i == N) start[N] = E;
}

__global__ void fill_kernel(const int* __restrict__ recv, const int* __restrict__ start,
                            int* __restrict__ cursor, int* __restrict__ eidx, int E) {
    int e = blockIdx.x * blockDim.x + threadIdx.x;
    if (e >= E) return;
    int r = recv[e];
    int p = atomicAdd(&cursor[r], 1);
    eidx[start[r] + p] = e;
}

// ============================ weight folds ============================

// Wvo = Wv @ Wo ; bvo = bv @ Wo
__global__ void fold_wvo_kernel(const float* __restrict__ Wv, const float* __restrict__ Wo,
                                const float* __restrict__ bv,
                                float* __restrict__ Wvo, float* __restrict__ bvo) {
    int j = threadIdx.x;
    int i = blockIdx.x;
    if (i < D) {
        float acc = 0.f;
        for (int k = 0; k < D; ++k) acc += Wv[(size_t)i * D + k] * Wo[(size_t)k * D + j];
        Wvo[(size_t)i * D + j] = acc;
    } else {
        float acc = 0.f;
        for (int k = 0; k < D; ++k) acc += bv[k] * Wo[(size_t)k * D + j];
        bvo[j] = acc;
    }
}

// Wqk[i][j] = sum_t Wq[i][t]*Wk[j][t]; bqk[j] = sum_t bq[t]*Wk[j][t];
// wqb[i] = sum_t Wq[i][t]*bk[t]; bqb = bq.bk
__global__ void fold_wqk_kernel(const float* __restrict__ Wq, const float* __restrict__ Wk,
                                const float* __restrict__ bq, const float* __restrict__ bk,
                                float* __restrict__ Wqk, float* __restrict__ bqk,
                                float* __restrict__ wqb, float* __restrict__ bqb) {
    int j = threadIdx.x;
    int i = blockIdx.x;
    if (i < D) {
        float acc = 0.f;
        for (int t = 0; t < D; ++t) acc += Wq[(size_t)i * D + t] * Wk[(size_t)j * D + t];
        Wqk[(size_t)i * D + j] = acc;
    } else if (i == D) {
        float acc = 0.f;
        for (int t = 0; t < D; ++t) acc += bq[t] * Wk[(size_t)j * D + t];
        bqk[j] = acc;
    } else {
        float acc = 0.f;
        for (int t = 0; t < D; ++t) acc += Wq[(size_t)j * D + t] * bk[t];
        wqb[j] = acc;
        if (j == 0) {
            float b = 0.f;
            for (int t = 0; t < D; ++t) b += bq[t] * bk[t];
            *bqb = b;
        }
    }
}

// ============================ per-node gather kernels ============================

// summed[n] = sum over edges of node n (one wave per node, float2 per lane)
__global__ __launch_bounds__(256) void nodesum_kernel(
        const float* __restrict__ msg, const int* __restrict__ eidx,
        const int* __restrict__ start, float* __restrict__ summed, int N) {
    int wave = threadIdx.x >> 6;
    int lane = threadIdx.x & 63;
    int n = blockIdx.x * 4 + wave;
    if (n >= N) return;
    int s0 = start[n], s1 = start[n + 1];
    float2 acc = make_float2(0.f, 0.f);
    for (int j = s0; j < s1; ++j) {
        int e = eidx[j];
        float2 mm = ((const float2*)(msg + (size_t)e * D))[lane];
        acc.x += mm.x;
        acc.y += mm.y;
    }
    ((float2*)(summed + (size_t)n * D))[lane] = acc;
}

// Fused flash-style: per node, one pass over edges.
// score_e = (m_e . qk[n] + qb[n]) / sqrt(D); online softmax; S[n] = sum attn_e * m_e
__global__ __launch_bounds__(256) void attn_kernel(
        const float* __restrict__ msg, const int* __restrict__ eidx,
        const int* __restrict__ start, const float* __restrict__ qk,
        const float* __restrict__ qb, float* __restrict__ S,
        float* __restrict__ sumexp, int N) {
    int wave = threadIdx.x >> 6;
    int lane = threadIdx.x & 63;
    int n = blockIdx.x * 4 + wave;
    if (n >= N) return;
    int s0 = start[n], s1 = start[n + 1];
    float2 q = ((const float2*)(qk + (size_t)n * D))[lane];
    float qbn = qb[n];
    float m = -3.4e38f, ssum = 0.f;
    float2 acc = make_float2(0.f, 0.f);

    float2 cur;
    if (s0 < s1) {
        int e0 = eidx[s0];
        cur = ((const float2*)(msg + (size_t)e0 * D))[lane];
    }
    for (int j = s0; j < s1; ++j) {
        // prefetch next row while we reduce the current one
        float2 nxt;
        if (j + 1 < s1) {
            int e1 = eidx[j + 1];
            nxt = ((const float2*)(msg + (size_t)e1 * D))[lane];
        }
        float p = cur.x * q.x + cur.y * q.y;
#pragma unroll
        for (int off = 1; off < 64; off <<= 1) p += __shfl_xor(p, off);
        float sc = (p + qbn) * RSQRT_D;
        float nm = fmaxf(m, sc);
        float scale = __expf(m - nm);    // 0 on first iter (m = -inf)
        float ee = __expf(sc - nm);
        ssum = ssum * scale + ee;
        acc.x = acc.x * scale + ee * cur.x;
        acc.y = acc.y * scale + ee * cur.y;
        m = nm;
        cur = nxt;
    }
    float w = 1.f / (ssum + 1e-8f);      // empty node: acc=0 -> S=0
    ((float2*)(S + (size_t)n * D))[lane] = make_float2(acc.x * w, acc.y * w);
    if (lane == 0) sumexp[n] = ssum;
}

// ============================ small dense GEMMs ============================

// C[n][j] = sum_i A[n][i]*B[i][j] (+bias[j]) (+ se/(se+1e-8) * bvec[j])
#define GN 32
__global__ __launch_bounds__(256) void gemm128_kernel(
        const float* __restrict__ A, const float* __restrict__ B,
        float* __restrict__ C,
        const float* __restrict__ bias,
        const float* __restrict__ sumexp,
        const float* __restrict__ bvec,
        int N) {
    __shared__ float Bs[D * D];
    __shared__ float As[GN * D];
    int t = threadIdx.x;
    const float4* Bg4 = (const float4*)B;
    float4* Bs4 = (float4*)Bs;
#pragma unroll
    for (int k = 0; k < 16; ++k) Bs4[t + 256 * k] = Bg4[t + 256 * k];
    int n0 = blockIdx.x * GN;
    const float4* Ag4 = (const float4*)(A + (size_t)n0 * D);
    float4* As4 = (float4*)As;
#pragma unroll
    for (int k = 0; k < 4; ++k) As4[t + 256 * k] = Ag4[t + 256 * k];
    __syncthreads();

    int c = t & 31;
    int slot = t >> 5;
    float4 acc[4];
#pragma unroll
    for (int u = 0; u < 4; ++u) acc[u] = make_float4(0.f, 0.f, 0.f, 0.f);
    const float4* Bsr = (const float4*)Bs;
    for (int i = 0; i < D; i += 4) {
        float4 a[4];
#pragma unroll
        for (int u = 0; u < 4; ++u) a[u] = *(const float4*)(As + (slot + 8 * u) * D + i);
#pragma unroll
        for (int ii = 0; ii < 4; ++ii) {
            float4 b = Bsr[(i + ii) * 32 + c];
#pragma unroll
            for (int u = 0; u < 4; ++u) {
                float av = (ii == 0) ? a[u].x : (ii == 1) ? a[u].y : (ii == 2) ? a[u].z : a[u].w;
                acc[u].x += av * b.x; acc[u].y += av * b.y;
                acc[u].z += av * b.z; acc[u].w += av * b.w;
            }
        }
    }
    float4 bias4 = bias ? ((const float4*)bias)[c] : make_float4(0.f, 0.f, 0.f, 0.f);
    float4 bv4 = bvec ? ((const float4*)bvec)[c] : make_float4(0.f, 0.f, 0.f, 0.f);
#pragma unroll
    for (int u = 0; u < 4; ++u) {
        int n = n0 + slot + 8 * u;
        if (n >= N) continue;
        float4 r = acc[u];
        r.x += bias4.x; r.y += bias4.y; r.z += bias4.z; r.w += bias4.w;
        if (sumexp) {
            float se = sumexp[n];
            float sa = se / (se + 1e-8f);
            r.x += sa * bv4.x; r.y += sa * bv4.y; r.z += sa * bv4.z; r.w += sa * bv4.w;
        }
        ((float4*)(C + (size_t)n * D))[c] = r;
    }
}

// qb[n] = sum_k A[n][k]*v[k] + addc[0]   (wave per node)
__global__ void rowdot_kernel(const float* __restrict__ A, const float* __restrict__ v,
                              const float* __restrict__ addc,
                              float* __restrict__ out, int N) {
    int g = blockIdx.x * blockDim.x + threadIdx.x;
    int lane = g & 63;
    int n = g >> 6;
    if (n >= N) return;
    const float2* a2 = (const float2*)(A + (size_t)n * D);
    const float2* v2 = (const float2*)v;
    float2 a = a2[lane], b = v2[lane];
    float s = a.x * b.x + a.y * b.y;
#pragma unroll
    for (int off = 32; off; off >>= 1) s += __shfl_down(s, off);
    if (lane == 0) out[n] = s + addc[0];
}

// ============================ launch ============================

extern "C" void kernel_launch(void* const* d_in, const int* in_sizes, int n_in,
                              void* d_out, int out_size, void* d_ws, size_t ws_size,
                              hipStream_t stream) {
    const float* msg = (const float*)d_in[0];
    const int* recv = (const int*)d_in[1];
    const float* Wk = (const float*)d_in[3];
    const float* bk = (const float*)d_in[4];
    const float* Wv = (const float*)d_in[5];
    const float* bv = (const float*)d_in[6];
    const float* Wq = (const float*)d_in[7];
    const float* bq = (const float*)d_in[8];
    const float* Wo = (const float*)d_in[9];
    const float* bo = (const float*)d_in[10];
    float* out = (float*)d_out;

    int E = in_sizes[0] / D;
    int N = out_size / D;

    char* wsb = (char*)d_ws;
    size_t o = 0;
    auto alloc = [&](size_t elems) { void* p = wsb + o; o += elems * 4; return p; };

    int* cnt    = (int*)alloc(N);
    int* cursor = (int*)alloc(N);       // [cnt,cursor] zeroed below
    int* start  = (int*)alloc(N + 1);
    int* excl   = (int*)alloc(N);
    int* bsum   = (int*)alloc(SCAN_B);
    int* eidx   = (int*)alloc(E);
    float* summed = (float*)alloc((size_t)N * D);
    float* qk     = (float*)alloc((size_t)N * D);
    float* qb     = (float*)alloc(N);
    float* S      = (float*)alloc((size_t)N * D);
    float* sumexp = (float*)alloc(N);
    float* Wqk    = (float*)alloc(D * D);
    float* bqk    = (float*)alloc(D);
    float* wqb    = (float*)alloc(D);
    float* bqb    = (float*)alloc(1);
    float* Wvo    = (float*)alloc(D * D);
    float* bvo    = (float*)alloc(D);

    hipMemsetAsync(cnt, 0, 2 * (size_t)N * sizeof(int), stream);  // cnt + cursor adjacent

    // weight folds (independent of edge data)
    fold_wvo_kernel<<<D + 1, D, 0, stream>>>(Wv, Wo, bv, Wvo, bvo);
    fold_wqk_kernel<<<D + 2, D, 0, stream>>>(Wq, Wk, bq, bk, Wqk, bqk, wqb, bqb);

    // CSR build
    int nbE = (E + 255) / 256;
    int nbS = (N + SCAN_B - 1) / SCAN_B;
    hist_kernel<<<nbE, 256, 0, stream>>>(recv, cnt, E);
    scan1_kernel<<<nbS, SCAN_B, 0, stream>>>(cnt, excl, bsum, N);
    scan2_kernel<<<1, SCAN_B, 0, stream>>>(bsum, nbS);
    scan3_kernel<<<(N + 1 + SCAN_B - 1) / SCAN_B, SCAN_B, 0, stream>>>(excl, bsum, start, N, E);
    fill_kernel<<<nbE, 256, 0, stream>>>(recv, start, cursor, eidx, E);

    // pass 1: per-node segment sum (gather, no atomics)
    nodesum_kernel<<<(N + 3) / 4, 256, 0, stream>>>(msg, eidx, start, summed, N);

    // qk = summed @ Wqk + bqk ; qb = summed . wqb + bqb
    gemm128_kernel<<<(N + GN - 1) / GN, 256, 0, stream>>>(summed, Wqk, qk, bqk, nullptr, nullptr, N);
    rowdot_kernel<<<(N * 64 + 255) / 256, 256, 0, stream>>>(summed, wqb, bqb, qb, N);

    // pass 2: fused score + online softmax + weighted sum (single message read)
    attn_kernel<<<(N + 3) / 4, 256, 0, stream>>>(msg, eidx, start, qk, qb, S, sumexp, N);

    // out = S @ Wvo + (se/(se+1e-8))*bvo + bo
    gemm128_kernel<<<(N + GN - 1) / GN, 256, 0, stream>>>(S, Wvo, out, bo, sumexp, bvo, N);
}